// Round 7
// baseline (241.203 us; speedup 1.0000x reference)
//
#include <hip/hip_runtime.h>
#include <math.h>

// LightweightConv: B=16, T=4000, C=512, H=8, K=31, PAD=15.
// out[b,t,c] = sum_k wn[c%8][k] * x[b, t-15+k, c] + bias[c%8],  wn = softmax(w)
// (B,T,C) contiguous in C -> lane = channel, coalesced 4B/lane.
// Floor: 262 MB unique traffic -> ~42 us @ 6.3 TB/s.
// R5 diagnosis: latency-bound. VGPR=48 proves compiler sank the 46 window
// loads into the FMA loop (~3 loads in flight). FETCH=183MB (1.4x input):
// adjacent t-chunks on different XCDs -> halo misses L2.
// R6 fix: sched_barrier(0) to force all-loads-first (46 in flight/wave) +
// bijective XCD swizzle so consecutive t-chunks share one XCD's L2.

constexpr int NB   = 16;
constexpr int NT   = 4000;
constexpr int NC   = 512;
constexpr int NH   = 8;
constexpr int NK   = 31;
constexpr int CPAD = 15;

constexpr int CH   = 16;            // outputs per thread
constexpr int HALO = NK - 1;        // 30
constexpr int WIN  = CH + HALO;     // 46 loads per thread
constexpr int NTC  = NT / CH;       // 250 t-chunks
constexpr int NCG  = NC / 256;      // 2 channel groups
constexpr int NWG  = NTC * NCG * NB;// 8000 (divisible by 8)
constexpr int NXCD = 8;

// --- pre-kernel: softmax-normalize the (8,31) weight table into d_ws ---
__global__ __launch_bounds__(64) void softmax_w_kernel(
    const float* __restrict__ w, float* __restrict__ wn)
{
    const int h = threadIdx.x;
    if (h >= NH) return;
    float v[NK];
    float m = -1e30f;
    #pragma unroll
    for (int k = 0; k < NK; ++k) { v[k] = w[h * NK + k]; m = fmaxf(m, v[k]); }
    float s = 0.0f;
    #pragma unroll
    for (int k = 0; k < NK; ++k) { v[k] = __expf(v[k] - m); s += v[k]; }
    const float inv = 1.0f / s;
    #pragma unroll
    for (int k = 0; k < NK; ++k) wn[h * NK + k] = v[k] * inv;
}

// --- main kernel: one thread = one (b, c, 16-output t-chunk) ---
__global__ __launch_bounds__(256, 4) void lconv_kernel(
    const float* __restrict__ x,
    const float* __restrict__ wn,
    const float* __restrict__ bias,
    float* __restrict__ out)
{
    // Bijective XCD swizzle: dispatch round-robins blockIdx.x across 8 XCDs.
    // lin = (orig%8)*1000 + orig/8 gives each XCD a contiguous run of lin;
    // decoding with t-chunk FASTEST in lin makes consecutive t-chunks (which
    // share 30/46 input rows) land on the same XCD -> halo hits its L2.
    const int orig = blockIdx.x;
    const int lin  = (orig % NXCD) * (NWG / NXCD) + orig / NXCD;
    const int tc   = lin % NTC;
    const int rest = lin / NTC;
    const int cg   = rest % NCG;
    const int b    = rest / NCG;

    const int c  = cg * 256 + threadIdx.x;   // channel, lane-contiguous
    const int t0 = tc * CH;
    const int h  = c & (NH - 1);

    const float* xb = x   + (size_t)b * NT * NC + c;
    float*       ob = out + (size_t)b * NT * NC + c;

    // normalized weights for this head (992 B table, cache-broadcast)
    float wr[NK];
    #pragma unroll
    for (int k = 0; k < NK; ++k) wr[k] = wn[h * NK + k];
    const float bv = bias[h];

    // full window: win[i] = x[b, t0-15+i, c] -- 46 independent loads
    float win[WIN];
    if (t0 >= CPAD && t0 + CH - 1 + CPAD < NT) {
        #pragma unroll
        for (int i = 0; i < WIN; ++i)
            win[i] = xb[(size_t)(t0 - CPAD + i) * NC];
    } else {
        #pragma unroll
        for (int i = 0; i < WIN; ++i) {
            const int t = t0 - CPAD + i;
            win[i] = (t >= 0 && t < NT) ? xb[(size_t)t * NC] : 0.0f;
        }
    }

    // Fence: forbid the scheduler from sinking loads into the FMA loop.
    // All 46 loads must be issued above this point -> ~11.8 KB in flight/wave.
    __builtin_amdgcn_sched_barrier(0);

    // 16 outputs, fully unrolled, static indices only
    #pragma unroll
    for (int j = 0; j < CH; ++j) {
        float acc = bv;
        #pragma unroll
        for (int k = 0; k < NK; ++k) acc = fmaf(win[j + k], wr[k], acc);
        ob[(size_t)(t0 + j) * NC] = acc;
    }
}

extern "C" void kernel_launch(void* const* d_in, const int* in_sizes, int n_in,
                              void* d_out, int out_size, void* d_ws, size_t ws_size,
                              hipStream_t stream) {
    const float* x    = (const float*)d_in[0];   // (B, T, C) f32
    const float* w    = (const float*)d_in[1];   // (H, 1, K) f32
    const float* bias = (const float*)d_in[2];   // (H,) f32
    float*       out  = (float*)d_out;           // (B, T, C) f32
    float*       wnrm = (float*)d_ws;            // 8*31 f32 normalized weights

    softmax_w_kernel<<<1, 64, 0, stream>>>(w, wnrm);
    lconv_kernel<<<NWG, 256, 0, stream>>>(x, wnrm, bias, out);
}